// Round 19
// baseline (311.938 us; speedup 1.0000x reference)
//
#include <hip/hip_runtime.h>
#include <hip/hip_bf16.h>

#define T_SEQ 4096
#define HID 2048
#define NQH 16
#define NKVH 4
#define HD 128
#define KVW (NKVH * HD)          // 512
#define KVSTRIDE 1024            // fused [k|v] projection width
#define QGW (NQH * HD * 2)       // 4096

typedef __attribute__((ext_vector_type(8))) short short8;
typedef __attribute__((ext_vector_type(4))) float f32x4;
typedef __attribute__((ext_vector_type(16))) float f32x16;
typedef __attribute__((ext_vector_type(2))) unsigned uint2v;
typedef __hip_bfloat16 bf16;

__device__ inline float bf2f(bf16 v) { return __bfloat162float(v); }
__device__ inline bf16 f2bf(float v) { return __float2bfloat16(v); }

__device__ inline void storeC(float* p, float v) { *p = v; }
__device__ inline void storeC(bf16* p, float v) { *p = f2bf(v); }

// native single-instruction exp2 (v_exp_f32); args are always <= 0 and finite
#if __has_builtin(__builtin_amdgcn_exp2f)
__device__ inline float fexp2(float x) { return __builtin_amdgcn_exp2f(x); }
#else
extern "C" __device__ float __ocml_native_exp2_f32(float);
__device__ inline float fexp2(float x) { return __ocml_native_exp2_f32(x); }
#endif

#if __has_builtin(__builtin_amdgcn_permlane32_swap)
#define HAVE_PLSWAP 1
#endif

// async global->LDS, 16B per lane; LDS dest = wave-uniform base + lane*16
__device__ inline void gload16(const void* g, void* l) {
    __builtin_amdgcn_global_load_lds(
        (const __attribute__((address_space(1))) void*)g,
        (__attribute__((address_space(3))) void*)l, 16, 0, 0);
}

__device__ inline unsigned pack2(float a, float b) {
    union { bf16 h[2]; unsigned u; } x;
    x.h[0] = f2bf(a); x.h[1] = f2bf(b);
    return x.u;
}
union U8 { unsigned u[4]; short8 s; };

// ---------------- prep_all: x->bf16 copy | rope tables | Wq/Wk/Wv transpose ----------------
// (Wo transpose moved to mid_prep: only needed by the final GEMM, off this critical path)
__global__ void prep_all(const float* __restrict__ x, bf16* __restrict__ bx,
                         const int* __restrict__ pos, const float* __restrict__ inv_freq,
                         float* __restrict__ cosT, float* __restrict__ sinT,
                         const float* __restrict__ Wq, const float* __restrict__ Wk,
                         const float* __restrict__ Wv,
                         bf16* __restrict__ bWq, bf16* __restrict__ bKV) {
    __shared__ float tile[32][33];
    const int b = blockIdx.x, tid = threadIdx.x;
    if (b < 8192) {
        int id = (b * 256 + tid) * 4;
        float4 v = *(const float4*)(x + id);
        bf16 tmp[4] = {f2bf(v.x), f2bf(v.y), f2bf(v.z), f2bf(v.w)};
        *(uint2*)(bx + id) = *(uint2*)tmp;
        return;
    }
    if (b < 9216) {
        int id = (b - 8192) * 256 + tid;          // T_SEQ*64 ids
        int t = id >> 6, i = id & 63;
        float f = (float)pos[t] * inv_freq[i];
        cosT[id] = cosf(f);
        sinT[id] = sinf(f);
        return;
    }
    // Wq|Wk|Wv transpose: fp32 [2048][C] -> bf16 [C][2048]  (160 x 64 tiles)
    const int tx = tid & 31, ty = tid >> 5;
    const float* src; bf16* dst; int C, cs, r0;
    {
        int idx = b - 9216;                        // 160 x 64
        int c0 = (idx % 160) * 32;
        r0 = (idx / 160) * 32;
        if (c0 < QGW)            { src = Wq; dst = bWq; C = QGW; cs = c0; }
        else if (c0 < QGW + KVW) { src = Wk; dst = bKV; C = KVW; cs = c0 - QGW; }
        else                     { src = Wv; dst = bKV + (long)KVW * HID; C = KVW; cs = c0 - QGW - KVW; }
    }
#pragma unroll
    for (int k = 0; k < 4; ++k)
        tile[ty + 8 * k][tx] = src[(long)(r0 + ty + 8 * k) * C + cs + tx];
    __syncthreads();
#pragma unroll
    for (int k = 0; k < 4; ++k)
        dst[(long)(cs + ty + 8 * k) * HID + r0 + tx] = f2bf(tile[tx][ty + 8 * k]);
}

// ---------------- mid_prep: transpose_v | Wo transpose | fused QK RMSNorm+RoPE ----------------
// Block ranges: [0,2048) V transpose; [2048,6144) Wo transpose; [6144,...) norm_rope.
__global__ void mid_prep(bf16* __restrict__ qg, bf16* __restrict__ kvb, bf16* __restrict__ vT,
                         const float* __restrict__ Wo, bf16* __restrict__ bWo,
                         const float* __restrict__ qw, const float* __restrict__ kw,
                         const float* __restrict__ cosT, const float* __restrict__ sinT,
                         float qScale) {
    __shared__ float ftile[32][33];
    const int b = blockIdx.x, tid = threadIdx.x;
    if (b < 2048) {
        bf16 (*tile)[33] = (bf16(*)[33])ftile;
        const int tx = tid & 31, ty = tid >> 5;
        const int d0 = (b & 15) * 32, t0 = (b >> 4) * 32;
#pragma unroll
        for (int k = 0; k < 4; ++k)
            tile[ty + 8 * k][tx] = kvb[(long)(t0 + ty + 8 * k) * KVSTRIDE + KVW + d0 + tx];
        __syncthreads();
#pragma unroll
        for (int k = 0; k < 4; ++k)
            vT[(long)(d0 + ty + 8 * k) * T_SEQ + t0 + tx] = tile[tx][ty + 8 * k];
        return;
    }
    if (b < 6144) {     // Wo fp32 [2048][2048] -> bf16 transpose (64 x 64 tiles)
        const int tx = tid & 31, ty = tid >> 5;
        int idx = b - 2048;
        int cs = (idx % 64) * 32, r0 = (idx / 64) * 32;
#pragma unroll
        for (int k = 0; k < 4; ++k)
            ftile[ty + 8 * k][tx] = Wo[(long)(r0 + ty + 8 * k) * HID + cs + tx];
        __syncthreads();
#pragma unroll
        for (int k = 0; k < 4; ++k)
            bWo[(long)(cs + ty + 8 * k) * HID + r0 + tx] = f2bf(ftile[tx][ty + 8 * k]);
        return;
    }
    const int bb = b - 6144;
    const int sub = tid >> 6, lane = tid & 63;
    const int NQB = (T_SEQ * NQH) / 4;   // 16384 q-blocks
    bf16* p; const float* w; float sc; int t;
    if (bb < NQB) {
        int row = bb * 4 + sub;
        t = row >> 4;
        int h = row & 15;
        p = qg + (long)t * QGW + h * (HD * 2);
        w = qw; sc = qScale;
    } else {
        int row = (bb - NQB) * 4 + sub;
        t = row >> 2;
        int h = row & 3;
        p = kvb + (long)t * KVSTRIDE + h * HD;
        w = kw; sc = 1.0f;
    }
    float x1 = bf2f(p[lane]), x2 = bf2f(p[lane + 64]);
    float ss = x1 * x1 + x2 * x2;
    ss += __shfl_xor(ss, 1);
    ss += __shfl_xor(ss, 2);
    ss += __shfl_xor(ss, 4);
    ss += __shfl_xor(ss, 8);
    ss += __shfl_xor(ss, 16);
    ss += __shfl_xor(ss, 32);
    float r = rsqrtf(ss * (1.0f / 128.0f) + 1e-6f);
    float c = cosT[t * 64 + lane], s = sinT[t * 64 + lane];
    float n1 = x1 * r * w[lane], n2 = x2 * r * w[lane + 64];
    p[lane] = f2bf((n1 * c - n2 * s) * sc);
    p[lane + 64] = f2bf((n2 * c + n1 * s) * sc);
}

// ---------------- GEMM 128x64 (m97 structure, 4 waves stacked in M) for kv ----------------
template <typename OutT>
__global__ __launch_bounds__(256) void gemm_bt64(const bf16* __restrict__ A,
                                                 const bf16* __restrict__ Bt,
                                                 OutT* __restrict__ C, int M, int N, int K) {
    __shared__ __align__(16) bf16 As[128 * 32];
    __shared__ __align__(16) bf16 Bs[64 * 32];
    const int tid = threadIdx.x, lane = tid & 63, wv = tid >> 6;
    const int nwg = gridDim.x * gridDim.y;
    const int orig = blockIdx.y * gridDim.x + blockIdx.x;
    const int wg = (orig & 7) * (nwg >> 3) + (orig >> 3);   // nwg % 8 == 0
    const int bm = (wg / gridDim.x) * 128, bn = (wg % gridDim.x) * 64;
    const int wm = wv * 32;                 // 4 waves stacked along M
    const int lr = lane & 15, lg = lane >> 4;
    f32x4 acc[2][4] = {};
    const int srow = tid >> 2, skg = (tid & 3) * 8;   // 0..63 rows, 4 col-groups
    const bf16* aP = A + (long)(bm + srow) * K + skg;
    const bf16* bP = Bt + (long)(bn + srow) * K + skg;
    bf16* asBase = As + wv * 512;   // lane-linear: wave writes 64*16B
    bf16* bsBase = Bs + wv * 512;
    for (int kt = 0; kt < K; kt += 32) {
        __syncthreads();  // previous tile consumed
        gload16(aP + kt, asBase);
        gload16(aP + (long)64 * K + kt, asBase + 2048);
        gload16(bP + kt, bsBase);
        __syncthreads();  // drains vmcnt -> tile visible
        short8 af[2], bfv[4];
#pragma unroll
        for (int m = 0; m < 2; ++m)
            af[m] = *(const short8*)(As + (wm + m * 16 + lr) * 32 + lg * 8);
#pragma unroll
        for (int n = 0; n < 4; ++n)
            bfv[n] = *(const short8*)(Bs + (n * 16 + lr) * 32 + lg * 8);
#pragma unroll
        for (int m = 0; m < 2; ++m)
#pragma unroll
            for (int n = 0; n < 4; ++n)
                acc[m][n] = __builtin_amdgcn_mfma_f32_16x16x32_bf16(af[m], bfv[n], acc[m][n], 0, 0, 0);
    }
#pragma unroll
    for (int m = 0; m < 2; ++m)
#pragma unroll
        for (int n = 0; n < 4; ++n)
#pragma unroll
            for (int j = 0; j < 4; ++j) {
                int r = bm + wm + m * 16 + lg * 4 + j;
                int c = bn + n * 16 + lr;
                storeC(&C[(long)r * N + c], acc[m][n][j]);
            }
}

// ---------------- GEMM 256xBN, BK=64, 8-phase counted-vmcnt schedule + XCD swizzle ----------------
template <int BN, typename OutT>
__global__ __launch_bounds__(512, 2) void gemm256(const bf16* __restrict__ A,
                                                  const bf16* __restrict__ Bt,
                                                  OutT* __restrict__ C, int M, int N, int K) {
    constexpr int FN = BN / 64;            // B frags per wave (4 or 2)
    __shared__ __align__(16) bf16 As[2][256 * 64];
    __shared__ __align__(16) bf16 Bs[2][BN * 64];
    const int tid = threadIdx.x, lane = tid & 63, wv = tid >> 6;
    const int wr = wv >> 2, wc = wv & 3;        // 2 x 4 wave grid
    const int lr = lane & 15, lg = lane >> 4;
    const int nwg = gridDim.x * gridDim.y;
    const int flat = blockIdx.y * gridDim.x + blockIdx.x;
    const int wg = (flat & 7) * (nwg >> 3) + (flat >> 3);   // nwg % 8 == 0
    const int bm = (wg / gridDim.x) * 256, bn = (wg % gridDim.x) * BN;
    const int nt = K >> 6;

    // staging source mapping (pre-swizzled): thread -> (row tid>>3, phys slot tid&7)
    const int srow = tid >> 3, sslot = tid & 7;
    const int slotLog = sslot ^ (srow & 7);
    const bf16* aSrc = A + (long)(bm + srow) * K + slotLog * 8;
    const bf16* bSrc = Bt + (long)(bn + srow) * K + slotLog * 8;

    auto stageA = [&](int T, int hh) {
        const int b_ = T & 1;
        gload16(aSrc + (long)(hh * 128) * K + (long)T * 64, &As[b_][hh * 8192 + wv * 512]);
        gload16(aSrc + (long)(hh * 128 + 64) * K + (long)T * 64, &As[b_][hh * 8192 + 4096 + wv * 512]);
    };
    auto stageB = [&](int T, int hh) {
        const int b_ = T & 1;
        gload16(bSrc + (long)(hh * 128) * K + (long)T * 64, &Bs[b_][hh * 8192 + wv * 512]);
        gload16(bSrc + (long)(hh * 128 + 64) * K + (long)T * 64, &Bs[b_][hh * 8192 + 4096 + wv * 512]);
    };

    // swizzled ds_read slot offsets (elements); row&7 == lr&7 for all frag rows
    int slotE[2];
#pragma unroll
    for (int ks = 0; ks < 2; ++ks) slotE[ks] = ((ks * 4 + lg) ^ (lr & 7)) * 8;

    f32x4 acc[8][FN] = {};

    // prologue: B(0), A(0), B(1)
    stageB(0, 0);
    if constexpr (BN == 256) stageB(0, 1);
    stageA(0, 0); stageA(0, 1);
    stageB(1, 0);
    if constexpr (BN == 256) stageB(1, 1);
    if constexpr (BN == 256) asm volatile("s_waitcnt vmcnt(4)" ::: "memory");
    else                     asm volatile("s_waitcnt vmcnt(2)" ::: "memory");
    __builtin_amdgcn_s_barrier();

    for (int t = 0; t < nt; ++t) {
        const int cur = t & 1;
        const bf16* Acur = As[cur];
        const bf16* Bcur = Bs[cur];
        short8 bfr[FN * 2];
#pragma unroll
        for (int q = 0; q < 4; ++q) {
            if (q == 0) {
#pragma unroll
                for (int fn = 0; fn < FN; ++fn)
#pragma unroll
                    for (int ks = 0; ks < 2; ++ks)
                        bfr[fn * 2 + ks] =
                            *(const short8*)(Bcur + (wc * (BN / 4) + fn * 16 + lr) * 64 + slotE[ks]);
            }
            short8 afr[4];
#pragma unroll
            for (int f2 = 0; f2 < 2; ++f2)
#pragma unroll
                for (int ks = 0; ks < 2; ++ks)
                    afr[f2 * 2 + ks] =
                        *(const short8*)(Acur + (wr * 128 + (q * 2 + f2) * 16 + lr) * 64 + slotE[ks]);
            // stage one half-tile per phase
            if (q == 0) { if (t + 1 < nt) stageA(t + 1, 0); }
            else if (q == 1) { if (t + 1 < nt) stageA(t + 1, 1); }
            else if (q == 2) { if (t + 2 < nt) stageB(t + 2, 0); }
            else { if (BN == 256 && t + 2 < nt) stageB(t + 2, 1); }
            __builtin_amdgcn_s_barrier();
            __builtin_amdgcn_s_setprio(1);
#pragma unroll
            for (int f2 = 0; f2 < 2; ++f2)
#pragma unroll
                for (int fn = 0; fn < FN; ++fn)
#pragma unroll
                    for (int ks = 0; ks < 2; ++ks)
                        acc[q * 2 + f2][fn] = __builtin_amdgcn_mfma_f32_16x16x32_bf16(
                            afr[f2 * 2 + ks], bfr[fn * 2 + ks], acc[q * 2 + f2][fn], 0, 0, 0);
            __builtin_amdgcn_s_setprio(0);
            if (q == 3) {
                if constexpr (BN == 256) asm volatile("s_waitcnt vmcnt(4)" ::: "memory");
                else                     asm volatile("s_waitcnt vmcnt(2)" ::: "memory");
            }
            __builtin_amdgcn_s_barrier();
        }
    }

#pragma unroll
    for (int fm = 0; fm < 8; ++fm)
#pragma unroll
        for (int fn = 0; fn < FN; ++fn)
#pragma unroll
            for (int j = 0; j < 4; ++j) {
                int r = bm + wr * 128 + fm * 16 + lg * 4 + j;
                int c = bn + wc * (BN / 4) + fn * 16 + lr;
                storeC(&C[(long)r * N + c], acc[fm][fn][j]);
            }
}

// ---------------- causal GQA flash attention v14 + gate ----------------
// attn13 + T5 setprio(1) around the PV MFMA cluster only (critical-path consumer;
// wave role diversity from 2 co-resident blocks at different chunks).
__global__ __launch_bounds__(256, 2) void attn14(const bf16* __restrict__ qg,
                                                 const bf16* __restrict__ kvb,
                                                 const bf16* __restrict__ vT,
                                                 bf16* __restrict__ aout) {
    __shared__ __align__(16) bf16 Ks[2][64 * 128];   // [key][d], XOR (row&15)<<4 on 16B slots
    __shared__ __align__(16) bf16 Vs[3][128 * 64];   // [d][key], XOR (row&7)<<4, triple buf
    const int tid = threadIdx.x, lane = tid & 63, wv = tid >> 6;
    const int q32 = lane & 31, g = lane >> 5;
    const int bid = blockIdx.x;              // 512
    const int xcd = bid & 7, slot = bid >> 3;
    const int h = 2 * xcd + (slot & 1);      // kv-head pinned to XCD pair
    const int chunk = 31 - (slot >> 1);      // heavy chunks dispatch first
    const int hk = h >> 2;
    const int q0w = chunk * 128 + wv * 32;
    const int nkt = 2 * chunk + 2;
    const int qr = q0w + q32;

    // Q B-frags: lane holds Q[q0w+q32][k = kk*16 + g*8 + i] (pre-scaled by scale*log2e)
    short8 bq[8];
    {
        const bf16* qp = qg + (long)(q0w + q32) * QGW + h * (HD * 2) + g * 8;
#pragma unroll
        for (int kk = 0; kk < 8; ++kk) bq[kk] = *(const short8*)(qp + kk * 16);
    }

    f32x16 acc[4] = {};     // O[q-row=krow(r,g)][d = n*32 + q32]
    f32x16 accL = {};       // l[q-row=krow(r,g)] via ones-column PV
    float m2 = -1e30f;
    const short8 vONE = {16256, 16256, 16256, 16256, 16256, 16256, 16256, 16256}; // bf16 1.0

    const bf16* kS[4];
    const bf16* vS[4];
    int kOff[4], vOff[4];
#pragma unroll
    for (int i = 0; i < 4; ++i) {
        const int kc = wv * 4 + i;
        const int krow = kc * 4 + (lane >> 4);
        const int kcolB = ((lane & 15) * 16) ^ ((krow & 15) << 4);
        kS[i] = kvb + (long)krow * KVSTRIDE + hk * HD + (kcolB >> 1);
        kOff[i] = kc * 512;
        const int vc = wv * 4 + i;
        const int vrow = vc * 8 + (lane >> 3);
        const int vcolB = ((lane & 7) * 16) ^ ((vrow & 7) << 4);
        vS[i] = vT + (long)(hk * HD + vrow) * T_SEQ + (vcolB >> 1);
        vOff[i] = vc * 512;
    }

    auto stageK = [&](int T, int buf) {
        const long koff = (long)T * 64;
#pragma unroll
        for (int i = 0; i < 4; ++i) gload16(kS[i] + koff * KVSTRIDE, &Ks[buf][kOff[i]]);
    };
    auto stageV = [&](int T, int buf) {
        const long koff = (long)T * 64;
#pragma unroll
        for (int i = 0; i < 4; ++i) gload16(vS[i] + koff, &Vs[buf][vOff[i]]);
    };

    const int kSlotB = (g * 16) ^ ((q32 & 15) << 4);
    const int vSlotB = (g * 16) ^ ((q32 & 7) << 4);

    auto computeQK = [&](const bf16* KsB, f32x16& s0, f32x16& s1) {
#pragma unroll
        for (int kk = 0; kk < 8; ++kk) {
            const int ko = q32 * 128 + (((kk * 32) ^ kSlotB) >> 1);
            short8 ka0 = *(const short8*)(KsB + ko);
            short8 ka1 = *(const short8*)(KsB + ko + 4096);
            s0 = __builtin_amdgcn_mfma_f32_32x32x16_bf16(ka0, bq[kk], s0, 0, 0, 0);
            s1 = __builtin_amdgcn_mfma_f32_32x32x16_bf16(ka1, bq[kk], s1, 0, 0, 0);
        }
    };

    // ---- prologue: stage tile 0; QK(0); issue staging of tile 1 ----
    stageK(0, 0); stageV(0, 0);
    __syncthreads();
    f32x16 s0c = {}, s1c = {};
    computeQK(Ks[0], s0c, s1c);          // tile 0 computed by every wave
    if (nkt > 1) { stageK(1, 1); stageV(1, 1); }

    for (int kt = 0; kt < nkt; ++kt) {
        __syncthreads();   // tile kt+1 staged (own vmcnt drained per wave before barrier)
        // ---- QK(kt+1) off the critical path ----
        f32x16 s0n = {}, s1n = {};
        if ((kt + 1 < nkt) && ((kt + 1) * 64 <= q0w + 31))
            computeQK(Ks[(kt + 1) & 1], s0n, s1n);
        // ---- issue staging for tile kt+2 (K(kt)/V(kt-1) buffers are dead) ----
        if (kt + 2 < nkt) { stageK(kt + 2, kt & 1); stageV(kt + 2, (kt + 2) % 3); }
        const int key00 = kt * 64;
        if (key00 <= q0w + 31) {
            // ---- causal mask (diag tiles only) on held S ----
            if (key00 + 63 > q0w) {
#pragma unroll
                for (int r = 0; r < 16; ++r) {
                    const int krow = (r & 3) + 8 * (r >> 2) + 4 * g;
                    if (key00 + krow > qr) s0c[r] = -1e30f;
                    if (key00 + 32 + krow > qr) s1c[r] = -1e30f;
                }
            }
            // ---- max3-shaped tree reduce + lane-local softmax (native exp2) ----
            float t8[8];
#pragma unroll
            for (int i = 0; i < 8; ++i)
                t8[i] = fmaxf(fmaxf(fmaxf(s0c[i], s0c[i + 8]), s1c[i]), s1c[i + 8]);
            float u0 = fmaxf(fmaxf(t8[0], t8[1]), t8[2]);
            float u1 = fmaxf(fmaxf(t8[3], t8[4]), t8[5]);
            float u2 = fmaxf(t8[6], t8[7]);
            float mx = fmaxf(fmaxf(u0, u1), u2);
            mx = fmaxf(mx, __shfl_xor(mx, 32));
            float mn = m2, e = 1.f;
            bool need = false;
            if (mx > m2 + 8.f) { mn = mx; e = fexp2(m2 - mx); need = true; }
            m2 = mn;
#pragma unroll
            for (int r = 0; r < 16; ++r) {
                s0c[r] = fexp2(s0c[r] - mn);
                s1c[r] = fexp2(s1c[r] - mn);
            }
            if (__any(need)) {
#pragma unroll
                for (int r = 0; r < 16; ++r) {
                    const int krow = (r & 3) + 8 * (r >> 2) + 4 * g;
                    float er = __shfl(e, krow);
#pragma unroll
                    for (int n = 0; n < 4; ++n) acc[n][r] *= er;
                    accL[r] *= er;
                }
            }
            // ---- P -> PV A-frags in-register ----
            short8 pa[4];
#pragma unroll
            for (int half = 0; half < 2; ++half) {
                const f32x16& p = half ? s1c : s0c;
                unsigned lo0 = pack2(p[0], p[1]),   lo1 = pack2(p[2], p[3]);
                unsigned hi0 = pack2(p[4], p[5]),   hi1 = pack2(p[6], p[7]);
                unsigned lo2 = pack2(p[8], p[9]),   lo3 = pack2(p[10], p[11]);
                unsigned hi2 = pack2(p[12], p[13]), hi3 = pack2(p[14], p[15]);
                U8 a0, a1;
#ifdef HAVE_PLSWAP
                uint2v r0 = __builtin_amdgcn_permlane32_swap(lo0, hi0, false, false);
                uint2v r1 = __builtin_amdgcn_permlane32_swap(lo1, hi1, false, false);
                uint2v r2 = __builtin_amdgcn_permlane32_swap(lo2, hi2, false, false);
                uint2v r3 = __builtin_amdgcn_permlane32_swap(lo3, hi3, false, false);
                a0.u[0] = r0[0]; a0.u[1] = r1[0]; a0.u[2] = r0[1]; a0.u[3] = r1[1];
                a1.u[0] = r2[0]; a1.u[1] = r3[0]; a1.u[2] = r2[1]; a1.u[3] = r3[1];
#else
                unsigned sw0 = __shfl_xor(g ? lo0 : hi0, 32);
                unsigned sw1 = __shfl_xor(g ? lo1 : hi1, 32);
                unsigned sw2 = __shfl_xor(g ? lo2 : hi2, 32);
                unsigned sw3 = __shfl_xor(g ? lo3 : hi3, 32);
                a0.u[0] = g ? sw0 : lo0;  a0.u[1] = g ? sw1 : lo1;
                a0.u[2] = g ? hi0 : sw0;  a0.u[3] = g ? hi1 : sw1;
                a1.u[0] = g ? sw2 : lo2;  a1.u[1] = g ? sw3 : lo3;
                a1.u[2] = g ? hi2 : sw2;  a1.u[3] = g ? hi3 : sw3;
#endif
                pa[half * 2] = a0.s;
                pa[half * 2 + 1] = a1.s;
            }
            // ---- PV: acc[n] += pa[ks] * V[ks-slice][d]; accL += pa[ks] * 1 ----
            const bf16* VsB = Vs[kt % 3];
            __builtin_amdgcn_s_setprio(1);
#pragma unroll
            for (int ks = 0; ks < 4; ++ks) {
                const int vo = q32 * 64 + (((ks * 32) ^ vSlotB) >> 1);
#pragma unroll
                for (int n = 0; n < 4; ++n) {
                    short8 vb = *(const short8*)(VsB + vo + n * 2048);
                    acc[n] = __builtin_amdgcn_mfma_f32_32x32x16_bf16(pa[ks], vb, acc[n], 0, 0, 0);
                }
                accL = __builtin_amdgcn_mfma_f32_32x32x16_bf16(pa[ks], vONE, accL, 0, 0, 0);
            }
            __builtin_amdgcn_s_setprio(0);
        }
        s0c = s0n;
        s1c = s1n;
    }

    // ---- epilogue: normalize, gate, store (l is lane-local in accL) ----
#pragma unroll
    for (int r = 0; r < 16; ++r) {
        const int krow = (r & 3) + 8 * (r >> 2) + 4 * g;
        const float linv = 1.0f / accL[r];
        const long t = q0w + krow;
        const bf16* gp = qg + t * QGW + h * (HD * 2) + HD + q32;
        bf16* op = aout + t * (NQH * HD) + h * HD + q32;
#pragma unroll
        for (int n = 0; n < 4; ++n) {
            float gv = bf2f(gp[n * 32]);
            float o = acc[n][r] * linv * (1.f / (1.f + __expf(-gv)));
            op[n * 32] = f2bf(o);
        }
    }
}

extern "C" void kernel_launch(void* const* d_in, const int* in_sizes, int n_in,
                              void* d_out, int out_size, void* d_ws, size_t ws_size,
                              hipStream_t stream) {
    const float* x = (const float*)d_in[0];
    const int* pos = (const int*)d_in[1];
    const float* inv_freq = (const float*)d_in[2];
    const float* Wq = (const float*)d_in[3];
    const float* Wk = (const float*)d_in[4];
    const float* Wv = (const float*)d_in[5];
    const float* Wo = (const float*)d_in[6];
    const float* qw = (const float*)d_in[7];
    const float* kw = (const float*)d_in[8];
    float* out = (float*)d_out;

    char* ws = (char*)d_ws;
    float* cosT = (float*)ws;               ws += (long)T_SEQ * 64 * 4;
    float* sinT = (float*)ws;               ws += (long)T_SEQ * 64 * 4;
    bf16* bx = (bf16*)ws;                   ws += (long)T_SEQ * HID * 2;
    bf16* bWq = (bf16*)ws;                  ws += (long)QGW * HID * 2;
    bf16* bKV = (bf16*)ws;                  ws += (long)KVSTRIDE * HID * 2;   // [Wk^T ; Wv^T]
    bf16* bWo = (bf16*)ws;                  ws += (long)HID * HID * 2;
    bf16* qg = (bf16*)ws;                   ws += (long)T_SEQ * QGW * 2;
    bf16* kvb = (bf16*)ws;                  ws += (long)T_SEQ * KVSTRIDE * 2;
    bf16* aout = (bf16*)ws;                 ws += (long)T_SEQ * (NQH * HD) * 2;
    bf16* vT = (bf16*)bWq;  // alias: bWq consumed by qg GEMM before mid_prep runs

    prep_all<<<19456, 256, 0, stream>>>(x, bx, pos, inv_freq, cosT, sinT,
                                        Wq, Wk, Wv, bWq, bKV);

    gemm256<256, bf16><<<dim3(QGW / 256, T_SEQ / 256), 512, 0, stream>>>(bx, bWq, qg, T_SEQ, QGW, HID);
    gemm_bt64<bf16><<<dim3(KVSTRIDE / 64, T_SEQ / 128), 256, 0, stream>>>(bx, bKV, kvb, T_SEQ, KVSTRIDE, HID);

    // Q pre-scale folds softmax scale AND log2(e) for exp2-domain softmax
    mid_prep<<<2048 + 4096 + 20480, 256, 0, stream>>>(qg, kvb, vT, Wo, bWo, qw, kw, cosT, sinT,
                                                      0.08838834764831845f * 1.4426950408889634f);

    attn14<<<dim3(512), 256, 0, stream>>>(qg, kvb, vT, aout);

    gemm256<128, float><<<dim3(HID / 128, T_SEQ / 256), 512, 0, stream>>>(aout, bWo, out, T_SEQ, HID, NQH * HD);
}

// Round 20
// 303.521 us; speedup vs baseline: 1.0277x; 1.0277x over previous
//
#include <hip/hip_runtime.h>
#include <hip/hip_bf16.h>

#define T_SEQ 4096
#define HID 2048
#define NQH 16
#define NKVH 4
#define HD 128
#define KVW (NKVH * HD)          // 512
#define KVSTRIDE 1024            // fused [k|v] projection width
#define QGW (NQH * HD * 2)       // 4096

typedef __attribute__((ext_vector_type(8))) short short8;
typedef __attribute__((ext_vector_type(4))) float f32x4;
typedef __attribute__((ext_vector_type(16))) float f32x16;
typedef __attribute__((ext_vector_type(2))) unsigned uint2v;
typedef __hip_bfloat16 bf16;

__device__ inline float bf2f(bf16 v) { return __bfloat162float(v); }
__device__ inline bf16 f2bf(float v) { return __float2bfloat16(v); }

__device__ inline void storeC(float* p, float v) { *p = v; }
__device__ inline void storeC(bf16* p, float v) { *p = f2bf(v); }

// native single-instruction exp2 (v_exp_f32); args are always <= 0 and finite
#if __has_builtin(__builtin_amdgcn_exp2f)
__device__ inline float fexp2(float x) { return __builtin_amdgcn_exp2f(x); }
#else
extern "C" __device__ float __ocml_native_exp2_f32(float);
__device__ inline float fexp2(float x) { return __ocml_native_exp2_f32(x); }
#endif

#if __has_builtin(__builtin_amdgcn_permlane32_swap)
#define HAVE_PLSWAP 1
#endif

// async global->LDS, 16B per lane; LDS dest = wave-uniform base + lane*16
__device__ inline void gload16(const void* g, void* l) {
    __builtin_amdgcn_global_load_lds(
        (const __attribute__((address_space(1))) void*)g,
        (__attribute__((address_space(3))) void*)l, 16, 0, 0);
}

__device__ inline unsigned pack2(float a, float b) {
    union { bf16 h[2]; unsigned u; } x;
    x.h[0] = f2bf(a); x.h[1] = f2bf(b);
    return x.u;
}
union U8 { unsigned u[4]; short8 s; };

// ---------------- prep_all: x->bf16 copy | rope tables | Wq/Wk/Wv transpose ----------------
__global__ void prep_all(const float* __restrict__ x, bf16* __restrict__ bx,
                         const int* __restrict__ pos, const float* __restrict__ inv_freq,
                         float* __restrict__ cosT, float* __restrict__ sinT,
                         const float* __restrict__ Wq, const float* __restrict__ Wk,
                         const float* __restrict__ Wv,
                         bf16* __restrict__ bWq, bf16* __restrict__ bKV) {
    __shared__ float tile[32][33];
    const int b = blockIdx.x, tid = threadIdx.x;
    if (b < 8192) {
        int id = (b * 256 + tid) * 4;
        float4 v = *(const float4*)(x + id);
        bf16 tmp[4] = {f2bf(v.x), f2bf(v.y), f2bf(v.z), f2bf(v.w)};
        *(uint2*)(bx + id) = *(uint2*)tmp;
        return;
    }
    if (b < 9216) {
        int id = (b - 8192) * 256 + tid;          // T_SEQ*64 ids
        int t = id >> 6, i = id & 63;
        float f = (float)pos[t] * inv_freq[i];
        cosT[id] = cosf(f);
        sinT[id] = sinf(f);
        return;
    }
    // Wq|Wk|Wv transpose: fp32 [2048][C] -> bf16 [C][2048]  (160 x 64 tiles)
    const int tx = tid & 31, ty = tid >> 5;
    const float* src; bf16* dst; int C, cs, r0;
    {
        int idx = b - 9216;                        // 160 x 64
        int c0 = (idx % 160) * 32;
        r0 = (idx / 160) * 32;
        if (c0 < QGW)            { src = Wq; dst = bWq; C = QGW; cs = c0; }
        else if (c0 < QGW + KVW) { src = Wk; dst = bKV; C = KVW; cs = c0 - QGW; }
        else                     { src = Wv; dst = bKV + (long)KVW * HID; C = KVW; cs = c0 - QGW - KVW; }
    }
#pragma unroll
    for (int k = 0; k < 4; ++k)
        tile[ty + 8 * k][tx] = src[(long)(r0 + ty + 8 * k) * C + cs + tx];
    __syncthreads();
#pragma unroll
    for (int k = 0; k < 4; ++k)
        dst[(long)(cs + ty + 8 * k) * HID + r0 + tx] = f2bf(tile[tx][ty + 8 * k]);
}

// ---------------- mid_prep: transpose_v | Wo transpose | fused QK RMSNorm+RoPE ----------------
__global__ void mid_prep(bf16* __restrict__ qg, bf16* __restrict__ kvb, bf16* __restrict__ vT,
                         const float* __restrict__ Wo, bf16* __restrict__ bWo,
                         const float* __restrict__ qw, const float* __restrict__ kw,
                         const float* __restrict__ cosT, const float* __restrict__ sinT,
                         float qScale) {
    __shared__ float ftile[32][33];
    const int b = blockIdx.x, tid = threadIdx.x;
    if (b < 2048) {
        bf16 (*tile)[33] = (bf16(*)[33])ftile;
        const int tx = tid & 31, ty = tid >> 5;
        const int d0 = (b & 15) * 32, t0 = (b >> 4) * 32;
#pragma unroll
        for (int k = 0; k < 4; ++k)
            tile[ty + 8 * k][tx] = kvb[(long)(t0 + ty + 8 * k) * KVSTRIDE + KVW + d0 + tx];
        __syncthreads();
#pragma unroll
        for (int k = 0; k < 4; ++k)
            vT[(long)(d0 + ty + 8 * k) * T_SEQ + t0 + tx] = tile[tx][ty + 8 * k];
        return;
    }
    if (b < 6144) {     // Wo fp32 [2048][2048] -> bf16 transpose (64 x 64 tiles)
        const int tx = tid & 31, ty = tid >> 5;
        int idx = b - 2048;
        int cs = (idx % 64) * 32, r0 = (idx / 64) * 32;
#pragma unroll
        for (int k = 0; k < 4; ++k)
            ftile[ty + 8 * k][tx] = Wo[(long)(r0 + ty + 8 * k) * HID + cs + tx];
        __syncthreads();
#pragma unroll
        for (int k = 0; k < 4; ++k)
            bWo[(long)(cs + ty + 8 * k) * HID + r0 + tx] = f2bf(ftile[tx][ty + 8 * k]);
        return;
    }
    const int bb = b - 6144;
    const int sub = tid >> 6, lane = tid & 63;
    const int NQB = (T_SEQ * NQH) / 4;   // 16384 q-blocks
    bf16* p; const float* w; float sc; int t;
    if (bb < NQB) {
        int row = bb * 4 + sub;
        t = row >> 4;
        int h = row & 15;
        p = qg + (long)t * QGW + h * (HD * 2);
        w = qw; sc = qScale;
    } else {
        int row = (bb - NQB) * 4 + sub;
        t = row >> 2;
        int h = row & 3;
        p = kvb + (long)t * KVSTRIDE + h * HD;
        w = kw; sc = 1.0f;
    }
    float x1 = bf2f(p[lane]), x2 = bf2f(p[lane + 64]);
    float ss = x1 * x1 + x2 * x2;
    ss += __shfl_xor(ss, 1);
    ss += __shfl_xor(ss, 2);
    ss += __shfl_xor(ss, 4);
    ss += __shfl_xor(ss, 8);
    ss += __shfl_xor(ss, 16);
    ss += __shfl_xor(ss, 32);
    float r = rsqrtf(ss * (1.0f / 128.0f) + 1e-6f);
    float c = cosT[t * 64 + lane], s = sinT[t * 64 + lane];
    float n1 = x1 * r * w[lane], n2 = x2 * r * w[lane + 64];
    p[lane] = f2bf((n1 * c - n2 * s) * sc);
    p[lane + 64] = f2bf((n2 * c + n1 * s) * sc);
}

// ---------------- GEMM 128x64 (m97 structure, 4 waves stacked in M) for kv ----------------
template <typename OutT>
__global__ __launch_bounds__(256) void gemm_bt64(const bf16* __restrict__ A,
                                                 const bf16* __restrict__ Bt,
                                                 OutT* __restrict__ C, int M, int N, int K) {
    __shared__ __align__(16) bf16 As[128 * 32];
    __shared__ __align__(16) bf16 Bs[64 * 32];
    const int tid = threadIdx.x, lane = tid & 63, wv = tid >> 6;
    const int nwg = gridDim.x * gridDim.y;
    const int orig = blockIdx.y * gridDim.x + blockIdx.x;
    const int wg = (orig & 7) * (nwg >> 3) + (orig >> 3);   // nwg % 8 == 0
    const int bm = (wg / gridDim.x) * 128, bn = (wg % gridDim.x) * 64;
    const int wm = wv * 32;                 // 4 waves stacked along M
    const int lr = lane & 15, lg = lane >> 4;
    f32x4 acc[2][4] = {};
    const int srow = tid >> 2, skg = (tid & 3) * 8;   // 0..63 rows, 4 col-groups
    const bf16* aP = A + (long)(bm + srow) * K + skg;
    const bf16* bP = Bt + (long)(bn + srow) * K + skg;
    bf16* asBase = As + wv * 512;   // lane-linear: wave writes 64*16B
    bf16* bsBase = Bs + wv * 512;
    for (int kt = 0; kt < K; kt += 32) {
        __syncthreads();  // previous tile consumed
        gload16(aP + kt, asBase);
        gload16(aP + (long)64 * K + kt, asBase + 2048);
        gload16(bP + kt, bsBase);
        __syncthreads();  // drains vmcnt -> tile visible
        short8 af[2], bfv[4];
#pragma unroll
        for (int m = 0; m < 2; ++m)
            af[m] = *(const short8*)(As + (wm + m * 16 + lr) * 32 + lg * 8);
#pragma unroll
        for (int n = 0; n < 4; ++n)
            bfv[n] = *(const short8*)(Bs + (n * 16 + lr) * 32 + lg * 8);
#pragma unroll
        for (int m = 0; m < 2; ++m)
#pragma unroll
            for (int n = 0; n < 4; ++n)
                acc[m][n] = __builtin_amdgcn_mfma_f32_16x16x32_bf16(af[m], bfv[n], acc[m][n], 0, 0, 0);
    }
#pragma unroll
    for (int m = 0; m < 2; ++m)
#pragma unroll
        for (int n = 0; n < 4; ++n)
#pragma unroll
            for (int j = 0; j < 4; ++j) {
                int r = bm + wm + m * 16 + lg * 4 + j;
                int c = bn + n * 16 + lr;
                storeC(&C[(long)r * N + c], acc[m][n][j]);
            }
}

// ---------------- GEMM 256xBN, BK=64, 8-phase counted-vmcnt schedule + XCD swizzle ----------------
template <int BN, typename OutT>
__global__ __launch_bounds__(512, 2) void gemm256(const bf16* __restrict__ A,
                                                  const bf16* __restrict__ Bt,
                                                  OutT* __restrict__ C, int M, int N, int K) {
    constexpr int FN = BN / 64;            // B frags per wave (4 or 2)
    __shared__ __align__(16) bf16 As[2][256 * 64];
    __shared__ __align__(16) bf16 Bs[2][BN * 64];
    const int tid = threadIdx.x, lane = tid & 63, wv = tid >> 6;
    const int wr = wv >> 2, wc = wv & 3;        // 2 x 4 wave grid
    const int lr = lane & 15, lg = lane >> 4;
    const int nwg = gridDim.x * gridDim.y;
    const int flat = blockIdx.y * gridDim.x + blockIdx.x;
    const int wg = (flat & 7) * (nwg >> 3) + (flat >> 3);   // nwg % 8 == 0
    const int bm = (wg / gridDim.x) * 256, bn = (wg % gridDim.x) * BN;
    const int nt = K >> 6;

    // staging source mapping (pre-swizzled): thread -> (row tid>>3, phys slot tid&7)
    const int srow = tid >> 3, sslot = tid & 7;
    const int slotLog = sslot ^ (srow & 7);
    const bf16* aSrc = A + (long)(bm + srow) * K + slotLog * 8;
    const bf16* bSrc = Bt + (long)(bn + srow) * K + slotLog * 8;

    auto stageA = [&](int T, int hh) {
        const int b_ = T & 1;
        gload16(aSrc + (long)(hh * 128) * K + (long)T * 64, &As[b_][hh * 8192 + wv * 512]);
        gload16(aSrc + (long)(hh * 128 + 64) * K + (long)T * 64, &As[b_][hh * 8192 + 4096 + wv * 512]);
    };
    auto stageB = [&](int T, int hh) {
        const int b_ = T & 1;
        gload16(bSrc + (long)(hh * 128) * K + (long)T * 64, &Bs[b_][hh * 8192 + wv * 512]);
        gload16(bSrc + (long)(hh * 128 + 64) * K + (long)T * 64, &Bs[b_][hh * 8192 + 4096 + wv * 512]);
    };

    // swizzled ds_read slot offsets (elements); row&7 == lr&7 for all frag rows
    int slotE[2];
#pragma unroll
    for (int ks = 0; ks < 2; ++ks) slotE[ks] = ((ks * 4 + lg) ^ (lr & 7)) * 8;

    f32x4 acc[8][FN] = {};

    // prologue: B(0), A(0), B(1)
    stageB(0, 0);
    if constexpr (BN == 256) stageB(0, 1);
    stageA(0, 0); stageA(0, 1);
    stageB(1, 0);
    if constexpr (BN == 256) stageB(1, 1);
    if constexpr (BN == 256) asm volatile("s_waitcnt vmcnt(4)" ::: "memory");
    else                     asm volatile("s_waitcnt vmcnt(2)" ::: "memory");
    __builtin_amdgcn_s_barrier();

    for (int t = 0; t < nt; ++t) {
        const int cur = t & 1;
        const bf16* Acur = As[cur];
        const bf16* Bcur = Bs[cur];
        short8 bfr[FN * 2];
#pragma unroll
        for (int q = 0; q < 4; ++q) {
            if (q == 0) {
#pragma unroll
                for (int fn = 0; fn < FN; ++fn)
#pragma unroll
                    for (int ks = 0; ks < 2; ++ks)
                        bfr[fn * 2 + ks] =
                            *(const short8*)(Bcur + (wc * (BN / 4) + fn * 16 + lr) * 64 + slotE[ks]);
            }
            short8 afr[4];
#pragma unroll
            for (int f2 = 0; f2 < 2; ++f2)
#pragma unroll
                for (int ks = 0; ks < 2; ++ks)
                    afr[f2 * 2 + ks] =
                        *(const short8*)(Acur + (wr * 128 + (q * 2 + f2) * 16 + lr) * 64 + slotE[ks]);
            // stage one half-tile per phase
            if (q == 0) { if (t + 1 < nt) stageA(t + 1, 0); }
            else if (q == 1) { if (t + 1 < nt) stageA(t + 1, 1); }
            else if (q == 2) { if (t + 2 < nt) stageB(t + 2, 0); }
            else { if (BN == 256 && t + 2 < nt) stageB(t + 2, 1); }
            __builtin_amdgcn_s_barrier();
            __builtin_amdgcn_s_setprio(1);
#pragma unroll
            for (int f2 = 0; f2 < 2; ++f2)
#pragma unroll
                for (int fn = 0; fn < FN; ++fn)
#pragma unroll
                    for (int ks = 0; ks < 2; ++ks)
                        acc[q * 2 + f2][fn] = __builtin_amdgcn_mfma_f32_16x16x32_bf16(
                            afr[f2 * 2 + ks], bfr[fn * 2 + ks], acc[q * 2 + f2][fn], 0, 0, 0);
            __builtin_amdgcn_s_setprio(0);
            if (q == 3) {
                if constexpr (BN == 256) asm volatile("s_waitcnt vmcnt(4)" ::: "memory");
                else                     asm volatile("s_waitcnt vmcnt(2)" ::: "memory");
            }
            __builtin_amdgcn_s_barrier();
        }
    }

#pragma unroll
    for (int fm = 0; fm < 8; ++fm)
#pragma unroll
        for (int fn = 0; fn < FN; ++fn)
#pragma unroll
            for (int j = 0; j < 4; ++j) {
                int r = bm + wr * 128 + fm * 16 + lg * 4 + j;
                int c = bn + wc * (BN / 4) + fn * 16 + lr;
                storeC(&C[(long)r * N + c], acc[fm][fn][j]);
            }
}

// ---------------- causal GQA flash attention v13 + gate (no setprio — proven best) ----------------
__global__ __launch_bounds__(256, 2) void attn13(const bf16* __restrict__ qg,
                                                 const bf16* __restrict__ kvb,
                                                 const bf16* __restrict__ vT,
                                                 bf16* __restrict__ aout) {
    __shared__ __align__(16) bf16 Ks[2][64 * 128];   // [key][d], XOR (row&15)<<4 on 16B slots
    __shared__ __align__(16) bf16 Vs[3][128 * 64];   // [d][key], XOR (row&7)<<4, triple buf
    const int tid = threadIdx.x, lane = tid & 63, wv = tid >> 6;
    const int q32 = lane & 31, g = lane >> 5;
    const int bid = blockIdx.x;              // 512
    const int xcd = bid & 7, slot = bid >> 3;
    const int h = 2 * xcd + (slot & 1);      // kv-head pinned to XCD pair
    const int chunk = 31 - (slot >> 1);      // heavy chunks dispatch first
    const int hk = h >> 2;
    const int q0w = chunk * 128 + wv * 32;
    const int nkt = 2 * chunk + 2;
    const int qr = q0w + q32;

    // Q B-frags: lane holds Q[q0w+q32][k = kk*16 + g*8 + i] (pre-scaled by scale*log2e)
    short8 bq[8];
    {
        const bf16* qp = qg + (long)(q0w + q32) * QGW + h * (HD * 2) + g * 8;
#pragma unroll
        for (int kk = 0; kk < 8; ++kk) bq[kk] = *(const short8*)(qp + kk * 16);
    }

    f32x16 acc[4] = {};     // O[q-row=krow(r,g)][d = n*32 + q32]
    f32x16 accL = {};       // l[q-row=krow(r,g)] via ones-column PV
    float m2 = -1e30f;
    const short8 vONE = {16256, 16256, 16256, 16256, 16256, 16256, 16256, 16256}; // bf16 1.0

    const bf16* kS[4];
    const bf16* vS[4];
    int kOff[4], vOff[4];
#pragma unroll
    for (int i = 0; i < 4; ++i) {
        const int kc = wv * 4 + i;
        const int krow = kc * 4 + (lane >> 4);
        const int kcolB = ((lane & 15) * 16) ^ ((krow & 15) << 4);
        kS[i] = kvb + (long)krow * KVSTRIDE + hk * HD + (kcolB >> 1);
        kOff[i] = kc * 512;
        const int vc = wv * 4 + i;
        const int vrow = vc * 8 + (lane >> 3);
        const int vcolB = ((lane & 7) * 16) ^ ((vrow & 7) << 4);
        vS[i] = vT + (long)(hk * HD + vrow) * T_SEQ + (vcolB >> 1);
        vOff[i] = vc * 512;
    }

    auto stageK = [&](int T, int buf) {
        const long koff = (long)T * 64;
#pragma unroll
        for (int i = 0; i < 4; ++i) gload16(kS[i] + koff * KVSTRIDE, &Ks[buf][kOff[i]]);
    };
    auto stageV = [&](int T, int buf) {
        const long koff = (long)T * 64;
#pragma unroll
        for (int i = 0; i < 4; ++i) gload16(vS[i] + koff, &Vs[buf][vOff[i]]);
    };

    const int kSlotB = (g * 16) ^ ((q32 & 15) << 4);
    const int vSlotB = (g * 16) ^ ((q32 & 7) << 4);

    auto computeQK = [&](const bf16* KsB, f32x16& s0, f32x16& s1) {
#pragma unroll
        for (int kk = 0; kk < 8; ++kk) {
            const int ko = q32 * 128 + (((kk * 32) ^ kSlotB) >> 1);
            short8 ka0 = *(const short8*)(KsB + ko);
            short8 ka1 = *(const short8*)(KsB + ko + 4096);
            s0 = __builtin_amdgcn_mfma_f32_32x32x16_bf16(ka0, bq[kk], s0, 0, 0, 0);
            s1 = __builtin_amdgcn_mfma_f32_32x32x16_bf16(ka1, bq[kk], s1, 0, 0, 0);
        }
    };

    // ---- prologue: stage tile 0; QK(0); issue staging of tile 1 ----
    stageK(0, 0); stageV(0, 0);
    __syncthreads();
    f32x16 s0c = {}, s1c = {};
    computeQK(Ks[0], s0c, s1c);          // tile 0 computed by every wave
    if (nkt > 1) { stageK(1, 1); stageV(1, 1); }

    for (int kt = 0; kt < nkt; ++kt) {
        __syncthreads();   // tile kt+1 staged (own vmcnt drained per wave before barrier)
        // ---- QK(kt+1) off the critical path ----
        f32x16 s0n = {}, s1n = {};
        if ((kt + 1 < nkt) && ((kt + 1) * 64 <= q0w + 31))
            computeQK(Ks[(kt + 1) & 1], s0n, s1n);
        // ---- issue staging for tile kt+2 (K(kt)/V(kt-1) buffers are dead) ----
        if (kt + 2 < nkt) { stageK(kt + 2, kt & 1); stageV(kt + 2, (kt + 2) % 3); }
        const int key00 = kt * 64;
        if (key00 <= q0w + 31) {
            // ---- causal mask (diag tiles only) on held S ----
            if (key00 + 63 > q0w) {
#pragma unroll
                for (int r = 0; r < 16; ++r) {
                    const int krow = (r & 3) + 8 * (r >> 2) + 4 * g;
                    if (key00 + krow > qr) s0c[r] = -1e30f;
                    if (key00 + 32 + krow > qr) s1c[r] = -1e30f;
                }
            }
            // ---- max3-shaped tree reduce + lane-local softmax (native exp2) ----
            float t8[8];
#pragma unroll
            for (int i = 0; i < 8; ++i)
                t8[i] = fmaxf(fmaxf(fmaxf(s0c[i], s0c[i + 8]), s1c[i]), s1c[i + 8]);
            float u0 = fmaxf(fmaxf(t8[0], t8[1]), t8[2]);
            float u1 = fmaxf(fmaxf(t8[3], t8[4]), t8[5]);
            float u2 = fmaxf(t8[6], t8[7]);
            float mx = fmaxf(fmaxf(u0, u1), u2);
            mx = fmaxf(mx, __shfl_xor(mx, 32));
            float mn = m2, e = 1.f;
            bool need = false;
            if (mx > m2 + 8.f) { mn = mx; e = fexp2(m2 - mx); need = true; }
            m2 = mn;
#pragma unroll
            for (int r = 0; r < 16; ++r) {
                s0c[r] = fexp2(s0c[r] - mn);
                s1c[r] = fexp2(s1c[r] - mn);
            }
            if (__any(need)) {
#pragma unroll
                for (int r = 0; r < 16; ++r) {
                    const int krow = (r & 3) + 8 * (r >> 2) + 4 * g;
                    float er = __shfl(e, krow);
#pragma unroll
                    for (int n = 0; n < 4; ++n) acc[n][r] *= er;
                    accL[r] *= er;
                }
            }
            // ---- P -> PV A-frags in-register ----
            short8 pa[4];
#pragma unroll
            for (int half = 0; half < 2; ++half) {
                const f32x16& p = half ? s1c : s0c;
                unsigned lo0 = pack2(p[0], p[1]),   lo1 = pack2(p[2], p[3]);
                unsigned hi0 = pack2(p[4], p[5]),   hi1 = pack2(p[6], p[7]);
                unsigned lo2 = pack2(p[8], p[9]),   lo3 = pack2(p[10], p[11]);
                unsigned hi2 = pack2(p[12], p[13]), hi3 = pack2(p[14], p[15]);
                U8 a0, a1;
#ifdef HAVE_PLSWAP
                uint2v r0 = __builtin_amdgcn_permlane32_swap(lo0, hi0, false, false);
                uint2v r1 = __builtin_amdgcn_permlane32_swap(lo1, hi1, false, false);
                uint2v r2 = __builtin_amdgcn_permlane32_swap(lo2, hi2, false, false);
                uint2v r3 = __builtin_amdgcn_permlane32_swap(lo3, hi3, false, false);
                a0.u[0] = r0[0]; a0.u[1] = r1[0]; a0.u[2] = r0[1]; a0.u[3] = r1[1];
                a1.u[0] = r2[0]; a1.u[1] = r3[0]; a1.u[2] = r2[1]; a1.u[3] = r3[1];
#else
                unsigned sw0 = __shfl_xor(g ? lo0 : hi0, 32);
                unsigned sw1 = __shfl_xor(g ? lo1 : hi1, 32);
                unsigned sw2 = __shfl_xor(g ? lo2 : hi2, 32);
                unsigned sw3 = __shfl_xor(g ? lo3 : hi3, 32);
                a0.u[0] = g ? sw0 : lo0;  a0.u[1] = g ? sw1 : lo1;
                a0.u[2] = g ? hi0 : sw0;  a0.u[3] = g ? hi1 : sw1;
                a1.u[0] = g ? sw2 : lo2;  a1.u[1] = g ? sw3 : lo3;
                a1.u[2] = g ? hi2 : sw2;  a1.u[3] = g ? hi3 : sw3;
#endif
                pa[half * 2] = a0.s;
                pa[half * 2 + 1] = a1.s;
            }
            // ---- PV: acc[n] += pa[ks] * V[ks-slice][d]; accL += pa[ks] * 1 ----
            const bf16* VsB = Vs[kt % 3];
#pragma unroll
            for (int ks = 0; ks < 4; ++ks) {
                const int vo = q32 * 64 + (((ks * 32) ^ vSlotB) >> 1);
#pragma unroll
                for (int n = 0; n < 4; ++n) {
                    short8 vb = *(const short8*)(VsB + vo + n * 2048);
                    acc[n] = __builtin_amdgcn_mfma_f32_32x32x16_bf16(pa[ks], vb, acc[n], 0, 0, 0);
                }
                accL = __builtin_amdgcn_mfma_f32_32x32x16_bf16(pa[ks], vONE, accL, 0, 0, 0);
            }
        }
        s0c = s0n;
        s1c = s1n;
    }

    // ---- epilogue: normalize, gate, store (l is lane-local in accL) ----
#pragma unroll
    for (int r = 0; r < 16; ++r) {
        const int krow = (r & 3) + 8 * (r >> 2) + 4 * g;
        const float linv = 1.0f / accL[r];
        const long t = q0w + krow;
        const bf16* gp = qg + t * QGW + h * (HD * 2) + HD + q32;
        bf16* op = aout + t * (NQH * HD) + h * HD + q32;
#pragma unroll
        for (int n = 0; n < 4; ++n) {
            float gv = bf2f(gp[n * 32]);
            float o = acc[n][r] * linv * (1.f / (1.f + __expf(-gv)));
            op[n * 32] = f2bf(o);
        }
    }
}

extern "C" void kernel_launch(void* const* d_in, const int* in_sizes, int n_in,
                              void* d_out, int out_size, void* d_ws, size_t ws_size,
                              hipStream_t stream) {
    const float* x = (const float*)d_in[0];
    const int* pos = (const int*)d_in[1];
    const float* inv_freq = (const float*)d_in[2];
    const float* Wq = (const float*)d_in[3];
    const float* Wk = (const float*)d_in[4];
    const float* Wv = (const float*)d_in[5];
    const float* Wo = (const float*)d_in[6];
    const float* qw = (const float*)d_in[7];
    const float* kw = (const float*)d_in[8];
    float* out = (float*)d_out;

    char* ws = (char*)d_ws;
    float* cosT = (float*)ws;               ws += (long)T_SEQ * 64 * 4;
    float* sinT = (float*)ws;               ws += (long)T_SEQ * 64 * 4;
    bf16* bx = (bf16*)ws;                   ws += (long)T_SEQ * HID * 2;
    bf16* bWq = (bf16*)ws;                  ws += (long)QGW * HID * 2;
    bf16* bKV = (bf16*)ws;                  ws += (long)KVSTRIDE * HID * 2;   // [Wk^T ; Wv^T]
    bf16* bWo = (bf16*)ws;                  ws += (long)HID * HID * 2;
    bf16* qg = (bf16*)ws;                   ws += (long)T_SEQ * QGW * 2;
    bf16* kvb = (bf16*)ws;                  ws += (long)T_SEQ * KVSTRIDE * 2;
    bf16* aout = (bf16*)ws;                 ws += (long)T_SEQ * (NQH * HD) * 2;
    bf16* vT = (bf16*)bWq;  // alias: bWq consumed by qg GEMM before mid_prep runs

    prep_all<<<19456, 256, 0, stream>>>(x, bx, pos, inv_freq, cosT, sinT,
                                        Wq, Wk, Wv, bWq, bKV);

    gemm256<256, bf16><<<dim3(QGW / 256, T_SEQ / 256), 512, 0, stream>>>(bx, bWq, qg, T_SEQ, QGW, HID);
    gemm_bt64<bf16><<<dim3(KVSTRIDE / 64, T_SEQ / 128), 256, 0, stream>>>(bx, bKV, kvb, T_SEQ, KVSTRIDE, HID);

    // Q pre-scale folds softmax scale AND log2(e) for exp2-domain softmax
    mid_prep<<<2048 + 4096 + 20480, 256, 0, stream>>>(qg, kvb, vT, Wo, bWo, qw, kw, cosT, sinT,
                                                      0.08838834764831845f * 1.4426950408889634f);

    attn13<<<dim3(512), 256, 0, stream>>>(qg, kvb, vT, aout);

    gemm256<128, float><<<dim3(HID / 128, T_SEQ / 256), 512, 0, stream>>>(aout, bWo, out, T_SEQ, HID, NQH * HD);
}